// Round 7
// baseline (569.075 us; speedup 1.0000x reference)
//
#include <hip/hip_runtime.h>
#include <stdint.h>

typedef __bf16 bf16;
typedef __bf16 bf16x8 __attribute__((ext_vector_type(8)));
typedef float f32x4 __attribute__((ext_vector_type(4)));

__device__ __forceinline__ float bfbits2f(uint32_t lo16) {
    uint32_t b = lo16 << 16;
    float f;
    __builtin_memcpy(&f, &b, 4);
    return f;
}

// ---- prep: W1T[h][f]=W1[f][h];
// WhwT[(r*128+c)*128 + k] = weight[r][k][c] (r<R), root[k][c] (r==R)
// tail: qc[i]=sum_j W2[i][j]*Wo[j], qc[128]=b2.Wo+bo
__global__ void k_prep(const float* __restrict__ W1, const float* __restrict__ weight,
                       const float* __restrict__ root, const float* __restrict__ W2,
                       const float* __restrict__ b2, const float* __restrict__ Wo,
                       const float* __restrict__ bo, bf16* __restrict__ W1T,
                       bf16* __restrict__ WhwT, float* __restrict__ qc, int R) {
    int total = 16384 * (R + 2);
    for (int i = blockIdx.x * blockDim.x + threadIdx.x; i < total + 129; i += gridDim.x * blockDim.x) {
        if (i < 16384) {
            int f = i >> 7, h = i & 127;
            W1T[h * 128 + f] = (bf16)W1[f * 128 + h];
        } else if (i < total) {
            int j = i - 16384;
            int r = j >> 14, rem = j & 16383, c = rem >> 7, k = rem & 127;
            float v = (r < R) ? weight[((size_t)(r * 128 + k)) * 128 + c] : root[(size_t)k * 128 + c];
            WhwT[(size_t)(r * 128 + c) * 128 + k] = (bf16)v;
        } else {
            int t = i - total;
            if (t < 128) {
                float s = 0.f;
                for (int j = 0; j < 128; j++) s += W2[t * 128 + j] * Wo[j];
                qc[t] = s;
            } else {
                float c = bo[0];
                for (int j = 0; j < 128; j++) c += b2[j] * Wo[j];
                qc[128] = c;
            }
        }
    }
}

// ---- CSR build (dst-keyed, N segments; payload (etype<<16)|src) ----
__global__ void k_hist(const int* __restrict__ dst, int* __restrict__ cnt, int E) {
    for (int e = blockIdx.x * blockDim.x + threadIdx.x; e < E; e += gridDim.x * blockDim.x)
        atomicAdd(&cnt[dst[e]], 1);
}

__global__ __launch_bounds__(256) void k_scan_blk(const int* __restrict__ cnt, int* __restrict__ bsum, int N) {
    int i = blockIdx.x * 256 + threadIdx.x;
    int v = (i < N) ? cnt[i] : 0;
#pragma unroll
    for (int d = 1; d < 64; d <<= 1) v += __shfl_xor(v, d);
    __shared__ int ws[4];
    if ((threadIdx.x & 63) == 0) ws[threadIdx.x >> 6] = v;
    __syncthreads();
    if (threadIdx.x == 0) bsum[blockIdx.x] = ws[0] + ws[1] + ws[2] + ws[3];
}

__global__ __launch_bounds__(256) void k_scan_top(int* __restrict__ bsum, int nb) {
    __shared__ int s[256];
    int t = threadIdx.x;
    int v = (t < nb) ? bsum[t] : 0;
    s[t] = v;
    __syncthreads();
#pragma unroll
    for (int d = 1; d < 256; d <<= 1) {
        int u = (t >= d) ? s[t - d] : 0;
        __syncthreads();
        s[t] += u;
        __syncthreads();
    }
    if (t < nb) bsum[t] = s[t] - v;  // exclusive
}

__global__ __launch_bounds__(256) void k_scan_apply(const int* __restrict__ cnt, const int* __restrict__ bsum,
                                                    int* __restrict__ row_off, int* __restrict__ cursor, int N) {
    int b = blockIdx.x, t = threadIdx.x;
    int i = b * 256 + t;
    int v = (i < N) ? cnt[i] : 0;
    int lane = t & 63, wid = t >> 6;
    int incl = v;
#pragma unroll
    for (int d = 1; d < 64; d <<= 1) {
        int u = __shfl_up(incl, d);
        if (lane >= d) incl += u;
    }
    __shared__ int ws[4];
    if (lane == 63) ws[wid] = incl;
    __syncthreads();
    int woff = 0;
    for (int wj = 0; wj < 4; wj++)
        if (wj < wid) woff += ws[wj];
    int excl = bsum[b] + woff + incl - v;
    if (i < N) {
        row_off[i] = excl;
        cursor[i] = excl;
        if (i == N - 1) row_off[N] = excl + v;
    }
}

// XCD-partitioned CSR fill (one XCD owns each contiguous csr region so lines
// fill fully before writeback). payload = (etype<<16)|src, requires N <= 65536.
__global__ void k_fill(const int* __restrict__ src, const int* __restrict__ dst,
                       const int* __restrict__ etype, int* __restrict__ cursor,
                       int* __restrict__ csr, int E, int pbase) {
    int p = blockIdx.x & 7;
    int bg = blockIdx.x >> 3;
    int nchunk = gridDim.x >> 3;
    int chunk = (E + nchunk - 1) / nchunk;
    int beg = bg * chunk, end = min(beg + chunk, E);
    int lo = p * pbase, hi = lo + pbase;
    for (int e = beg + (int)threadIdx.x; e < end; e += blockDim.x) {
        int d = dst[e];
        if (d >= lo && d < hi) {
            int pos = atomicAdd(&cursor[d], 1);
            csr[pos] = (etype[e] << 16) | src[e];
        }
    }
}

// ---- GEMM (layer 0): C[M x 128] = A_f32[M x 128] * B[128 x 128] (+bias), bf16 out
__global__ __launch_bounds__(256) void k_gemm0(const float* __restrict__ A, const bf16* __restrict__ BT,
                                               const float* __restrict__ bias, bf16* __restrict__ C, int M) {
    __shared__ bf16 sA[128 * 128];
    __shared__ bf16 sB[128 * 128];
    int tid = threadIdx.x;
    int m0 = blockIdx.x * 128;
#pragma unroll
    for (int i = 0; i < 8; i++) {
        int chunk = i * 256 + tid;
        int row = chunk >> 4, c16 = chunk & 15;
        int sw = ((c16 ^ (row & 7)) << 3);
        int gr = m0 + row;
        int4 va = {0, 0, 0, 0};
        if (gr < M) {
            const float* ap = A + (size_t)gr * 128 + (c16 << 3);
            float4 f0 = *reinterpret_cast<const float4*>(ap);
            float4 f1 = *reinterpret_cast<const float4*>(ap + 4);
            bf16 tmp[8] = {(bf16)f0.x, (bf16)f0.y, (bf16)f0.z, (bf16)f0.w,
                           (bf16)f1.x, (bf16)f1.y, (bf16)f1.z, (bf16)f1.w};
            __builtin_memcpy(&va, tmp, 16);
        }
        *reinterpret_cast<int4*>(&sA[row * 128 + sw]) = va;
        int4 vb = *reinterpret_cast<const int4*>(&BT[(size_t)row * 128 + (c16 << 3)]);
        *reinterpret_cast<int4*>(&sB[row * 128 + sw]) = vb;
    }
    __syncthreads();

    int lane = tid & 63, w = tid >> 6;
    int wm = (w >> 1) * 64, wn = (w & 1) * 64;
    int lr = lane & 15, lk = lane >> 4;
    f32x4 zero = {0.f, 0.f, 0.f, 0.f};
    f32x4 acc[4][4];
#pragma unroll
    for (int mi = 0; mi < 4; mi++)
#pragma unroll
        for (int ni = 0; ni < 4; ni++) acc[mi][ni] = zero;

#pragma unroll
    for (int kk = 0; kk < 4; kk++) {
        int c = (kk << 2) + lk;
        bf16x8 af[4], bfr[4];
#pragma unroll
        for (int mi = 0; mi < 4; mi++) {
            int r = wm + mi * 16 + lr;
            af[mi] = *reinterpret_cast<const bf16x8*>(&sA[r * 128 + ((c ^ (r & 7)) << 3)]);
        }
#pragma unroll
        for (int ni = 0; ni < 4; ni++) {
            int r = wn + ni * 16 + lr;
            bfr[ni] = *reinterpret_cast<const bf16x8*>(&sB[r * 128 + ((c ^ (r & 7)) << 3)]);
        }
#pragma unroll
        for (int mi = 0; mi < 4; mi++)
#pragma unroll
            for (int ni = 0; ni < 4; ni++)
                acc[mi][ni] = __builtin_amdgcn_mfma_f32_16x16x32_bf16(af[mi], bfr[ni], acc[mi][ni], 0, 0, 0);
    }

#pragma unroll
    for (int ni = 0; ni < 4; ni++) {
        int col = wn + ni * 16 + lr;
        float bia = bias[col];
#pragma unroll
        for (int mi = 0; mi < 4; mi++) {
#pragma unroll
            for (int j = 0; j < 4; j++) {
                int row = m0 + wm + mi * 16 + lk * 4 + j;
                if (row < M) C[(size_t)row * 128 + col] = (bf16)(acc[mi][ni][j] + bia);
            }
        }
    }
}

// ---- HW-table GEMM v2: HW[n][r*128+c] = (h[n] @ W_r)[c] (r=R: h@root).
// K=128 -> A-fragments live in registers, read DIRECTLY from h (L3-resident
// 12.8MB); B-fragments read directly from WhwT (L2-resident 295KB). No LDS,
// no barriers: 9-slice loop of pure {L2 loads -> MFMA -> nt store}. Output
// 115MB is nt-stored (write-no-allocate L3 observed in r6: agg3 FETCH ==
// unique table volume), keeping h/conv resident.
__global__ __launch_bounds__(256) void k_hwgemm(const bf16* __restrict__ h, const bf16* __restrict__ WhwT,
                                                bf16* __restrict__ HW, int M, int NS) {
    int tid = threadIdx.x;
    int m0 = blockIdx.x * 128;
    int lane = tid & 63, w = tid >> 6;
    int wm = (w >> 1) * 64, wn = (w & 1) * 64;
    int lr = lane & 15, lk = lane >> 4;
    int ldhw = NS * 128;

    // A-fragments resident in registers for all NS slices
    bf16x8 af[4][4];
#pragma unroll
    for (int kk = 0; kk < 4; kk++) {
        int c = (kk << 2) + lk;
#pragma unroll
        for (int mi = 0; mi < 4; mi++) {
            int gr = m0 + wm + mi * 16 + lr;
            gr = gr < M ? gr : M - 1;  // clamp; dup rows masked at write
            af[kk][mi] = *reinterpret_cast<const bf16x8*>(&h[(size_t)gr * 128 + (c << 3)]);
        }
    }

    for (int ns = 0; ns < NS; ns++) {
        f32x4 zero = {0.f, 0.f, 0.f, 0.f};
        f32x4 acc[4][4];
#pragma unroll
        for (int mi = 0; mi < 4; mi++)
#pragma unroll
            for (int ni = 0; ni < 4; ni++) acc[mi][ni] = zero;

#pragma unroll
        for (int kk = 0; kk < 4; kk++) {
            int c = (kk << 2) + lk;
            bf16x8 bfr[4];
#pragma unroll
            for (int ni = 0; ni < 4; ni++) {
                int o = ns * 128 + wn + ni * 16 + lr;
                bfr[ni] = *reinterpret_cast<const bf16x8*>(&WhwT[(size_t)o * 128 + (c << 3)]);
            }
#pragma unroll
            for (int mi = 0; mi < 4; mi++)
#pragma unroll
                for (int ni = 0; ni < 4; ni++)
                    acc[mi][ni] = __builtin_amdgcn_mfma_f32_16x16x32_bf16(af[kk][mi], bfr[ni], acc[mi][ni], 0, 0, 0);
        }

#pragma unroll
        for (int ni = 0; ni < 4; ni++) {
            int col = ns * 128 + wn + ni * 16 + lr;
#pragma unroll
            for (int mi = 0; mi < 4; mi++) {
#pragma unroll
                for (int j = 0; j < 4; j++) {
                    int row = m0 + wm + mi * 16 + lk * 4 + j;
                    if (row < M)
                        __builtin_nontemporal_store((bf16)acc[mi][ni][j], &HW[(size_t)row * ldhw + col]);
                }
            }
        }
    }
}

// ---- agg3 v2: conv[n] = sum_e HW[src_e][type_e] + HW[n][R] + bias, PLUS
// fused BN column stats. 8-deep load pipeline (r6: 4-deep @ VGPR=20 left
// MLP-starved -> 3 TB/s; fetch floor is ~107MB unique rows). 1024 blocks x
// 4 waves, contiguous node chunk per block (csr locality); per-thread
// register stats accumulation -> LDS reduce -> 1024x256 global atomics.
__global__ __launch_bounds__(256) void k_agg3(const bf16* __restrict__ HW, const int* __restrict__ row_off,
                                              const int* __restrict__ csr, const float* __restrict__ bias,
                                              float* __restrict__ conv, float* __restrict__ stats,
                                              int N, int ldhw, int R) {
    __shared__ float cs[128], cs2[128];
    int tid = threadIdx.x;
    int lane = tid & 63, w = tid >> 6;
    if (tid < 128) { cs[tid] = 0.f; cs2[tid] = 0.f; }
    __syncthreads();
    int c0 = lane * 2;
    float bia0 = bias[c0], bia1 = bias[c0 + 1];
    int chunk = (N + gridDim.x - 1) / gridDim.x;
    int nbeg = blockIdx.x * chunk;
    int nend = min(nbeg + chunk, N);
    float st0 = 0.f, st1 = 0.f, st20 = 0.f, st21 = 0.f;

    for (int n = nbeg + w; n < nend; n += 4) {
        float a0 = 0.f, a1 = 0.f;
        int beg = row_off[n], end = row_off[n + 1];
        int i = beg;
        for (; i + 8 <= end; i += 8) {
            int pp[8];
            uint32_t vv[8];
#pragma unroll
            for (int u = 0; u < 8; u++) pp[u] = csr[i + u];
#pragma unroll
            for (int u = 0; u < 8; u++)
                vv[u] = *reinterpret_cast<const uint32_t*>(
                    &HW[(size_t)(pp[u] & 0xffff) * ldhw + (((uint32_t)pp[u] >> 16) << 7) + c0]);
#pragma unroll
            for (int u = 0; u < 8; u++) {
                a0 += bfbits2f(vv[u] & 0xffffu);
                a1 += bfbits2f(vv[u] >> 16);
            }
        }
        for (; i < end; i++) {
            int p = csr[i];
            uint32_t v = *reinterpret_cast<const uint32_t*>(
                &HW[(size_t)(p & 0xffff) * ldhw + (((uint32_t)p >> 16) << 7) + c0]);
            a0 += bfbits2f(v & 0xffffu);
            a1 += bfbits2f(v >> 16);
        }
        uint32_t vr = *reinterpret_cast<const uint32_t*>(&HW[(size_t)n * ldhw + (R << 7) + c0]);
        a0 += bfbits2f(vr & 0xffffu) + bia0;
        a1 += bfbits2f(vr >> 16) + bia1;
        float2 st = {a0, a1};
        *reinterpret_cast<float2*>(&conv[(size_t)n * 128 + c0]) = st;
        st0 += a0; st20 += a0 * a0;
        st1 += a1; st21 += a1 * a1;
    }
    // reduce 4 waves' stats via LDS, then one global atomic per col per block
    atomicAdd(&cs[c0], st0); atomicAdd(&cs[c0 + 1], st1);
    atomicAdd(&cs2[c0], st20); atomicAdd(&cs2[c0 + 1], st21);
    __syncthreads();
    if (tid < 128) {
        atomicAdd(&stats[tid], cs[tid]);
        atomicAdd(&stats[128 + tid], cs2[tid]);
    }
}

// ---- finalize BN coefficients: bnp[c]=scale, bnp[128+c]=shift; re-zero stats
__global__ void k_bnfin(float* __restrict__ stats, const float* __restrict__ gamma,
                        const float* __restrict__ beta, float* __restrict__ bnp, float invN) {
    int t = threadIdx.x;
    float mu = stats[t] * invN;
    float var = stats[128 + t] * invN - mu * mu;
    float sc = gamma[t] * rsqrtf(var + 1e-5f);
    bnp[t] = sc;
    bnp[128 + t] = beta[t] - mu * sc;
    stats[t] = 0.f;
    stats[128 + t] = 0.f;
}

// ---- BN + ReLU + cast to bf16 (layer 1) ----
__global__ void k_bnrelu(const float* __restrict__ conv, const float* __restrict__ bnp,
                         bf16* __restrict__ h, int N) {
    int total = N * 32;
    for (int i = blockIdx.x * blockDim.x + threadIdx.x; i < total; i += gridDim.x * blockDim.x) {
        int c4 = (i & 31) << 2;
        float4 v = *reinterpret_cast<const float4*>(&conv[(size_t)i * 4]);
        const float* vv = &v.x;
        uint64_t pk = 0;
#pragma unroll
        for (int j = 0; j < 4; j++) {
            int c = c4 + j;
            float val = fmaxf(vv[j] * bnp[c] + bnp[128 + c], 0.f);
            unsigned short us = __builtin_bit_cast(unsigned short, (bf16)val);
            pk |= (uint64_t)us << (16 * j);
        }
        *reinterpret_cast<uint64_t*>(&h[(size_t)i * 4]) = pk;
    }
}

// ---- layer 2: out[n] = sigmoid(relu(bn(conv[n])) . q + c), fused, f32 out ----
__global__ __launch_bounds__(256) void k_bnout(const float* __restrict__ conv, const float* __restrict__ bnp,
                                               const float* __restrict__ qc, float* __restrict__ out, int N) {
    int wi = threadIdx.x >> 6;
    int n = blockIdx.x * 4 + wi;
    if (n >= N) return;
    int lane = threadIdx.x & 63;
    int c0 = lane * 2;
    float2 v = *reinterpret_cast<const float2*>(&conv[(size_t)n * 128 + c0]);
    float v0 = fmaxf(v.x * bnp[c0] + bnp[128 + c0], 0.f);
    float v1 = fmaxf(v.y * bnp[c0 + 1] + bnp[128 + c0 + 1], 0.f);
    float s = v0 * qc[c0] + v1 * qc[c0 + 1];
#pragma unroll
    for (int d = 1; d < 64; d <<= 1) s += __shfl_xor(s, d);
    if (lane == 0) out[n] = 1.f / (1.f + expf(-(s + qc[128])));
}

extern "C" void kernel_launch(void* const* d_in, const int* in_sizes, int n_in,
                              void* d_out, int out_size, void* d_ws, size_t ws_size,
                              hipStream_t stream) {
    const float* x      = (const float*)d_in[0];
    const int*   ei     = (const int*)d_in[1];
    const int*   etype  = (const int*)d_in[2];
    const float* W1     = (const float*)d_in[3];
    const float* b1     = (const float*)d_in[4];
    const float* weight = (const float*)d_in[5];
    const float* root   = (const float*)d_in[6];
    const float* bias_c = (const float*)d_in[7];
    const float* gamma  = (const float*)d_in[8];
    const float* beta   = (const float*)d_in[9];
    const float* W2     = (const float*)d_in[10];
    const float* b2     = (const float*)d_in[11];
    const float* Wo     = (const float*)d_in[12];
    const float* bo     = (const float*)d_in[13];
    float* out = (float*)d_out;

    int H = in_sizes[4];            // 128
    int F = in_sizes[3] / H;        // 128
    int N = in_sizes[0] / F;        // 50000
    int E = in_sizes[2];            // 800000
    int R = in_sizes[5] / (H * H);  // 8
    int NS = R + 1;                 // 9 output slices (R relations + root)
    int ldhw = NS * H;              // 1152

    const int* srcv = ei;
    const int* dstv = ei + E;

    char* p = (char*)d_ws;
    auto alloc = [&](size_t bytes) -> char* {
        char* r = p;
        p += (bytes + 255) & ~(size_t)255;
        return r;
    };
    bf16*  HW      = (bf16*)alloc((size_t)N * ldhw * 2);
    bf16*  h       = (bf16*)alloc((size_t)N * H * 2);
    float* conv    = (float*)alloc((size_t)N * H * 4);
    bf16*  WhwT    = (bf16*)alloc((size_t)ldhw * H * 2);
    bf16*  W1T     = (bf16*)alloc((size_t)F * H * 2);
    float* qc      = (float*)alloc(129 * 4);
    int*   cnt     = (int*)alloc((size_t)N * 4);
    int*   row_off = (int*)alloc((size_t)(N + 1) * 4);
    int*   cursor  = (int*)alloc((size_t)N * 4);
    int*   csr     = (int*)alloc((size_t)E * 4);
    float* stats   = (float*)alloc(256 * 4);
    float* bnp     = (float*)alloc(256 * 4);
    int*   bsum    = (int*)alloc(256 * 4);
    if ((size_t)(p - (char*)d_ws) > ws_size) return;

    int nb = (N + 255) / 256;  // <= 256 since N <= 65536 (required by csr packing)
    int pbase = (N + 7) / 8;   // dst-partition width for XCD-local csr fill

    hipMemsetAsync(cnt, 0, (size_t)N * 4, stream);
    hipMemsetAsync(stats, 0, 256 * 4, stream);
    k_prep<<<256, 256, 0, stream>>>(W1, weight, root, W2, b2, Wo, bo, W1T, WhwT, qc, R);
    k_hist<<<1024, 256, 0, stream>>>(dstv, cnt, E);
    k_scan_blk<<<nb, 256, 0, stream>>>(cnt, bsum, N);
    k_scan_top<<<1, 256, 0, stream>>>(bsum, nb);
    k_scan_apply<<<nb, 256, 0, stream>>>(cnt, bsum, row_off, cursor, N);
    k_fill<<<1024, 256, 0, stream>>>(srcv, dstv, etype, cursor, csr, E, pbase);

    int mb = (N + 127) / 128;
    k_gemm0<<<mb, 256, 0, stream>>>(x, W1T, b1, h, N);

    for (int l = 0; l < 2; l++) {
        k_hwgemm<<<mb, 256, 0, stream>>>(h, WhwT, HW, N, NS);
        k_agg3<<<1024, 256, 0, stream>>>(HW, row_off, csr, bias_c, conv, stats, N, ldhw, R);
        k_bnfin<<<1, 128, 0, stream>>>(stats, gamma, beta, bnp, 1.f / (float)N);
        if (l == 0)
            k_bnrelu<<<2048, 256, 0, stream>>>(conv, bnp, h, N);
        else
            k_bnout<<<(N + 3) / 4, 256, 0, stream>>>(conv, bnp, qc, out, N);
    }
}

// Round 8
// 540.871 us; speedup vs baseline: 1.0521x; 1.0521x over previous
//
#include <hip/hip_runtime.h>
#include <stdint.h>

typedef __bf16 bf16;
typedef __bf16 bf16x8 __attribute__((ext_vector_type(8)));
typedef float f32x4 __attribute__((ext_vector_type(4)));

__device__ __forceinline__ float bfbits2f(uint32_t lo16) {
    uint32_t b = lo16 << 16;
    float f;
    __builtin_memcpy(&f, &b, 4);
    return f;
}

// ---- prep: W1T[h][f]=W1[f][h];
// WhwT[(r*128+c)*128 + k] = weight[r][k][c] (r<R), root[k][c] (r==R)
// tail: qc[i]=sum_j W2[i][j]*Wo[j], qc[128]=b2.Wo+bo
__global__ void k_prep(const float* __restrict__ W1, const float* __restrict__ weight,
                       const float* __restrict__ root, const float* __restrict__ W2,
                       const float* __restrict__ b2, const float* __restrict__ Wo,
                       const float* __restrict__ bo, bf16* __restrict__ W1T,
                       bf16* __restrict__ WhwT, float* __restrict__ qc, int R) {
    int total = 16384 * (R + 2);
    for (int i = blockIdx.x * blockDim.x + threadIdx.x; i < total + 129; i += gridDim.x * blockDim.x) {
        if (i < 16384) {
            int f = i >> 7, h = i & 127;
            W1T[h * 128 + f] = (bf16)W1[f * 128 + h];
        } else if (i < total) {
            int j = i - 16384;
            int r = j >> 14, rem = j & 16383, c = rem >> 7, k = rem & 127;
            float v = (r < R) ? weight[((size_t)(r * 128 + k)) * 128 + c] : root[(size_t)k * 128 + c];
            WhwT[(size_t)(r * 128 + c) * 128 + k] = (bf16)v;
        } else {
            int t = i - total;
            if (t < 128) {
                float s = 0.f;
                for (int j = 0; j < 128; j++) s += W2[t * 128 + j] * Wo[j];
                qc[t] = s;
            } else {
                float c = bo[0];
                for (int j = 0; j < 128; j++) c += b2[j] * Wo[j];
                qc[128] = c;
            }
        }
    }
}

// ---- CSR build (dst-keyed, N segments; payload (etype<<16)|src) ----
__global__ void k_hist(const int* __restrict__ dst, int* __restrict__ cnt, int E) {
    for (int e = blockIdx.x * blockDim.x + threadIdx.x; e < E; e += gridDim.x * blockDim.x)
        atomicAdd(&cnt[dst[e]], 1);
}

__global__ __launch_bounds__(256) void k_scan_blk(const int* __restrict__ cnt, int* __restrict__ bsum, int N) {
    int i = blockIdx.x * 256 + threadIdx.x;
    int v = (i < N) ? cnt[i] : 0;
#pragma unroll
    for (int d = 1; d < 64; d <<= 1) v += __shfl_xor(v, d);
    __shared__ int ws[4];
    if ((threadIdx.x & 63) == 0) ws[threadIdx.x >> 6] = v;
    __syncthreads();
    if (threadIdx.x == 0) bsum[blockIdx.x] = ws[0] + ws[1] + ws[2] + ws[3];
}

__global__ __launch_bounds__(256) void k_scan_top(int* __restrict__ bsum, int nb) {
    __shared__ int s[256];
    int t = threadIdx.x;
    int v = (t < nb) ? bsum[t] : 0;
    s[t] = v;
    __syncthreads();
#pragma unroll
    for (int d = 1; d < 256; d <<= 1) {
        int u = (t >= d) ? s[t - d] : 0;
        __syncthreads();
        s[t] += u;
        __syncthreads();
    }
    if (t < nb) bsum[t] = s[t] - v;  // exclusive
}

__global__ __launch_bounds__(256) void k_scan_apply(const int* __restrict__ cnt, const int* __restrict__ bsum,
                                                    int* __restrict__ row_off, int* __restrict__ cursor, int N) {
    int b = blockIdx.x, t = threadIdx.x;
    int i = b * 256 + t;
    int v = (i < N) ? cnt[i] : 0;
    int lane = t & 63, wid = t >> 6;
    int incl = v;
#pragma unroll
    for (int d = 1; d < 64; d <<= 1) {
        int u = __shfl_up(incl, d);
        if (lane >= d) incl += u;
    }
    __shared__ int ws[4];
    if (lane == 63) ws[wid] = incl;
    __syncthreads();
    int woff = 0;
    for (int wj = 0; wj < 4; wj++)
        if (wj < wid) woff += ws[wj];
    int excl = bsum[b] + woff + incl - v;
    if (i < N) {
        row_off[i] = excl;
        cursor[i] = excl;
        if (i == N - 1) row_off[N] = excl + v;
    }
}

// XCD-partitioned CSR fill (one XCD owns each contiguous csr region so lines
// fill fully before writeback). payload = (etype<<16)|src, requires N <= 65536.
__global__ void k_fill(const int* __restrict__ src, const int* __restrict__ dst,
                       const int* __restrict__ etype, int* __restrict__ cursor,
                       int* __restrict__ csr, int E, int pbase) {
    int p = blockIdx.x & 7;
    int bg = blockIdx.x >> 3;
    int nchunk = gridDim.x >> 3;
    int chunk = (E + nchunk - 1) / nchunk;
    int beg = bg * chunk, end = min(beg + chunk, E);
    int lo = p * pbase, hi = lo + pbase;
    for (int e = beg + (int)threadIdx.x; e < end; e += blockDim.x) {
        int d = dst[e];
        if (d >= lo && d < hi) {
            int pos = atomicAdd(&cursor[d], 1);
            csr[pos] = (etype[e] << 16) | src[e];
        }
    }
}

// ---- GEMM (layer 0): C[M x 128] = A_f32[M x 128] * B[128 x 128] (+bias), bf16 out
__global__ __launch_bounds__(256) void k_gemm0(const float* __restrict__ A, const bf16* __restrict__ BT,
                                               const float* __restrict__ bias, bf16* __restrict__ C, int M) {
    __shared__ bf16 sA[128 * 128];
    __shared__ bf16 sB[128 * 128];
    int tid = threadIdx.x;
    int m0 = blockIdx.x * 128;
#pragma unroll
    for (int i = 0; i < 8; i++) {
        int chunk = i * 256 + tid;
        int row = chunk >> 4, c16 = chunk & 15;
        int sw = ((c16 ^ (row & 7)) << 3);
        int gr = m0 + row;
        int4 va = {0, 0, 0, 0};
        if (gr < M) {
            const float* ap = A + (size_t)gr * 128 + (c16 << 3);
            float4 f0 = *reinterpret_cast<const float4*>(ap);
            float4 f1 = *reinterpret_cast<const float4*>(ap + 4);
            bf16 tmp[8] = {(bf16)f0.x, (bf16)f0.y, (bf16)f0.z, (bf16)f0.w,
                           (bf16)f1.x, (bf16)f1.y, (bf16)f1.z, (bf16)f1.w};
            __builtin_memcpy(&va, tmp, 16);
        }
        *reinterpret_cast<int4*>(&sA[row * 128 + sw]) = va;
        int4 vb = *reinterpret_cast<const int4*>(&BT[(size_t)row * 128 + (c16 << 3)]);
        *reinterpret_cast<int4*>(&sB[row * 128 + sw]) = vb;
    }
    __syncthreads();

    int lane = tid & 63, w = tid >> 6;
    int wm = (w >> 1) * 64, wn = (w & 1) * 64;
    int lr = lane & 15, lk = lane >> 4;
    f32x4 zero = {0.f, 0.f, 0.f, 0.f};
    f32x4 acc[4][4];
#pragma unroll
    for (int mi = 0; mi < 4; mi++)
#pragma unroll
        for (int ni = 0; ni < 4; ni++) acc[mi][ni] = zero;

#pragma unroll
    for (int kk = 0; kk < 4; kk++) {
        int c = (kk << 2) + lk;
        bf16x8 af[4], bfr[4];
#pragma unroll
        for (int mi = 0; mi < 4; mi++) {
            int r = wm + mi * 16 + lr;
            af[mi] = *reinterpret_cast<const bf16x8*>(&sA[r * 128 + ((c ^ (r & 7)) << 3)]);
        }
#pragma unroll
        for (int ni = 0; ni < 4; ni++) {
            int r = wn + ni * 16 + lr;
            bfr[ni] = *reinterpret_cast<const bf16x8*>(&sB[r * 128 + ((c ^ (r & 7)) << 3)]);
        }
#pragma unroll
        for (int mi = 0; mi < 4; mi++)
#pragma unroll
            for (int ni = 0; ni < 4; ni++)
                acc[mi][ni] = __builtin_amdgcn_mfma_f32_16x16x32_bf16(af[mi], bfr[ni], acc[mi][ni], 0, 0, 0);
    }

#pragma unroll
    for (int ni = 0; ni < 4; ni++) {
        int col = wn + ni * 16 + lr;
        float bia = bias[col];
#pragma unroll
        for (int mi = 0; mi < 4; mi++) {
#pragma unroll
            for (int j = 0; j < 4; j++) {
                int row = m0 + wm + mi * 16 + lk * 4 + j;
                if (row < M) C[(size_t)row * 128 + col] = (bf16)(acc[mi][ni][j] + bia);
            }
        }
    }
}

// ---- HW-table GEMM v3: HW[n][r*128+c] = (h[n] @ W_r)[c] (r=R: h@root).
// r7 post-mortem: scattered 2B nt-stores -> WRITE 193MB @1.6TB/s (partial-line
// HBM transactions). v3: keep register A-frags (FETCH was 7.4MB, works), add
// LDS-transpose epilogue per slice -> coalesced 16B normal stores (16 lanes =
// 256B contiguous). 64-row tiles, 782 blocks (~3/CU) for balance.
__global__ __launch_bounds__(256) void k_hwgemm(const bf16* __restrict__ h, const bf16* __restrict__ WhwT,
                                                bf16* __restrict__ HW, int M, int NS) {
    __shared__ bf16 sT[64 * 128];  // 16 KB
    int tid = threadIdx.x;
    int m0 = blockIdx.x * 64;
    int lane = tid & 63, w = tid >> 6;
    int lr = lane & 15, lk = lane >> 4;
    int ldhw = NS * 128;

    // A-fragments resident in registers for all NS slices (rows m0+w*16+lr)
    bf16x8 af[4];
    {
        int gr = m0 + (w << 4) + lr;
        gr = gr < M ? gr : M - 1;  // clamp; dup rows masked at store
#pragma unroll
        for (int kk = 0; kk < 4; kk++) {
            int c = (kk << 2) + lk;
            af[kk] = *reinterpret_cast<const bf16x8*>(&h[(size_t)gr * 128 + (c << 3)]);
        }
    }

    int c8 = tid & 15;       // store-phase 16B chunk
    int rbase = tid >> 4;    // store-phase row base (0..15)

    for (int ns = 0; ns < NS; ns++) {
        f32x4 zero = {0.f, 0.f, 0.f, 0.f};
        f32x4 acc[8];
#pragma unroll
        for (int ni = 0; ni < 8; ni++) acc[ni] = zero;

#pragma unroll
        for (int kk = 0; kk < 4; kk++) {
            int c = (kk << 2) + lk;
#pragma unroll
            for (int ni = 0; ni < 8; ni++) {
                int o = ns * 128 + (ni << 4) + lr;
                bf16x8 bfr = *reinterpret_cast<const bf16x8*>(&WhwT[(size_t)o * 128 + (c << 3)]);
                acc[ni] = __builtin_amdgcn_mfma_f32_16x16x32_bf16(af[kk], bfr, acc[ni], 0, 0, 0);
            }
        }

        // stage tile in LDS (swizzled: elem col ^ ((row&7)<<3))
#pragma unroll
        for (int ni = 0; ni < 8; ni++) {
            int col = (ni << 4) + lr;
#pragma unroll
            for (int j = 0; j < 4; j++) {
                int rl = (w << 4) + (lk << 2) + j;
                sT[rl * 128 + (col ^ ((rl & 7) << 3))] = (bf16)acc[ni][j];
            }
        }
        __syncthreads();
        // coalesced 16B stores: lane group covers 256B contiguous per row
#pragma unroll
        for (int i = 0; i < 4; i++) {
            int rl = rbase + i * 16;
            int gr2 = m0 + rl;
            if (gr2 < M) {
                int4 v = *reinterpret_cast<const int4*>(&sT[rl * 128 + ((c8 ^ (rl & 7)) << 3)]);
                *reinterpret_cast<int4*>(&HW[(size_t)gr2 * ldhw + ns * 128 + (c8 << 3)]) = v;
            }
        }
        __syncthreads();
    }
}

// ---- agg3 v3: conv[n] = sum_e HW[src_e][type_e] + HW[n][R] + bias.
// r7 post-mortem: 1024-block chunked grid lost the 25k-block dynamic queue
// (4 blocks/CU, no replacement, imbalance). Revert to wave-per-node massive
// grid; keep the 8-deep load pipeline (VGPR=20 leaves huge headroom).
__global__ __launch_bounds__(128) void k_agg3(const bf16* __restrict__ HW, const int* __restrict__ row_off,
                                              const int* __restrict__ csr, const float* __restrict__ bias,
                                              float* __restrict__ conv, int N, int ldhw, int R) {
    int wi = threadIdx.x >> 6;
    int n = blockIdx.x * 2 + wi;
    if (n >= N) return;
    int lane = threadIdx.x & 63;
    int c0 = lane * 2;
    float a0 = 0.f, a1 = 0.f;
    int beg = row_off[n], end = row_off[n + 1];
    int i = beg;
    for (; i + 8 <= end; i += 8) {
        int pp[8];
        uint32_t vv[8];
#pragma unroll
        for (int u = 0; u < 8; u++) pp[u] = csr[i + u];
#pragma unroll
        for (int u = 0; u < 8; u++)
            vv[u] = *reinterpret_cast<const uint32_t*>(
                &HW[(size_t)(pp[u] & 0xffff) * ldhw + (((uint32_t)pp[u] >> 16) << 7) + c0]);
#pragma unroll
        for (int u = 0; u < 8; u++) {
            a0 += bfbits2f(vv[u] & 0xffffu);
            a1 += bfbits2f(vv[u] >> 16);
        }
    }
    for (; i < end; i++) {
        int p = csr[i];
        uint32_t v = *reinterpret_cast<const uint32_t*>(
            &HW[(size_t)(p & 0xffff) * ldhw + (((uint32_t)p >> 16) << 7) + c0]);
        a0 += bfbits2f(v & 0xffffu);
        a1 += bfbits2f(v >> 16);
    }
    uint32_t vr = *reinterpret_cast<const uint32_t*>(&HW[(size_t)n * ldhw + (R << 7) + c0]);
    a0 += bfbits2f(vr & 0xffffu) + bias[c0];
    a1 += bfbits2f(vr >> 16) + bias[c0 + 1];
    float2 st = {a0, a1};
    *reinterpret_cast<float2*>(&conv[(size_t)n * 128 + c0]) = st;
}

// ---- BN column stats over conv: stats[c]=sum, stats[128+c]=sumsq
__global__ __launch_bounds__(256) void k_stats(const float* __restrict__ conv, float* __restrict__ stats, int N) {
    __shared__ float cs[128], cs2[128];
    int tid = threadIdx.x;
    if (tid < 128) { cs[tid] = 0.f; cs2[tid] = 0.f; }
    __syncthreads();
    int c = (tid & 63) * 2;
    int rg = tid >> 6;  // 4 rows per block-iteration
    float s0 = 0.f, s20 = 0.f, s1 = 0.f, s21 = 0.f;
    for (int row = blockIdx.x * 4 + rg; row < N; row += gridDim.x * 4) {
        float2 v = *reinterpret_cast<const float2*>(&conv[(size_t)row * 128 + c]);
        s0 += v.x; s20 += v.x * v.x;
        s1 += v.y; s21 += v.y * v.y;
    }
    atomicAdd(&cs[c], s0); atomicAdd(&cs[c + 1], s1);
    atomicAdd(&cs2[c], s20); atomicAdd(&cs2[c + 1], s21);
    __syncthreads();
    if (tid < 128) {
        atomicAdd(&stats[tid], cs[tid]);
        atomicAdd(&stats[128 + tid], cs2[tid]);
    }
}

// ---- finalize BN coefficients: bnp[c]=scale, bnp[128+c]=shift; re-zero stats
__global__ void k_bnfin(float* __restrict__ stats, const float* __restrict__ gamma,
                        const float* __restrict__ beta, float* __restrict__ bnp, float invN) {
    int t = threadIdx.x;
    float mu = stats[t] * invN;
    float var = stats[128 + t] * invN - mu * mu;
    float sc = gamma[t] * rsqrtf(var + 1e-5f);
    bnp[t] = sc;
    bnp[128 + t] = beta[t] - mu * sc;
    stats[t] = 0.f;
    stats[128 + t] = 0.f;
}

// ---- BN + ReLU + cast to bf16 (layer 1) ----
__global__ void k_bnrelu(const float* __restrict__ conv, const float* __restrict__ bnp,
                         bf16* __restrict__ h, int N) {
    int total = N * 32;
    for (int i = blockIdx.x * blockDim.x + threadIdx.x; i < total; i += gridDim.x * blockDim.x) {
        int c4 = (i & 31) << 2;
        float4 v = *reinterpret_cast<const float4*>(&conv[(size_t)i * 4]);
        const float* vv = &v.x;
        uint64_t pk = 0;
#pragma unroll
        for (int j = 0; j < 4; j++) {
            int c = c4 + j;
            float val = fmaxf(vv[j] * bnp[c] + bnp[128 + c], 0.f);
            unsigned short us = __builtin_bit_cast(unsigned short, (bf16)val);
            pk |= (uint64_t)us << (16 * j);
        }
        *reinterpret_cast<uint64_t*>(&h[(size_t)i * 4]) = pk;
    }
}

// ---- layer 2: out[n] = sigmoid(relu(bn(conv[n])) . q + c), fused, f32 out ----
__global__ __launch_bounds__(256) void k_bnout(const float* __restrict__ conv, const float* __restrict__ bnp,
                                               const float* __restrict__ qc, float* __restrict__ out, int N) {
    int wi = threadIdx.x >> 6;
    int n = blockIdx.x * 4 + wi;
    if (n >= N) return;
    int lane = threadIdx.x & 63;
    int c0 = lane * 2;
    float2 v = *reinterpret_cast<const float2*>(&conv[(size_t)n * 128 + c0]);
    float v0 = fmaxf(v.x * bnp[c0] + bnp[128 + c0], 0.f);
    float v1 = fmaxf(v.y * bnp[c0 + 1] + bnp[128 + c0 + 1], 0.f);
    float s = v0 * qc[c0] + v1 * qc[c0 + 1];
#pragma unroll
    for (int d = 1; d < 64; d <<= 1) s += __shfl_xor(s, d);
    if (lane == 0) out[n] = 1.f / (1.f + expf(-(s + qc[128])));
}

extern "C" void kernel_launch(void* const* d_in, const int* in_sizes, int n_in,
                              void* d_out, int out_size, void* d_ws, size_t ws_size,
                              hipStream_t stream) {
    const float* x      = (const float*)d_in[0];
    const int*   ei     = (const int*)d_in[1];
    const int*   etype  = (const int*)d_in[2];
    const float* W1     = (const float*)d_in[3];
    const float* b1     = (const float*)d_in[4];
    const float* weight = (const float*)d_in[5];
    const float* root   = (const float*)d_in[6];
    const float* bias_c = (const float*)d_in[7];
    const float* gamma  = (const float*)d_in[8];
    const float* beta   = (const float*)d_in[9];
    const float* W2     = (const float*)d_in[10];
    const float* b2     = (const float*)d_in[11];
    const float* Wo     = (const float*)d_in[12];
    const float* bo     = (const float*)d_in[13];
    float* out = (float*)d_out;

    int H = in_sizes[4];            // 128
    int F = in_sizes[3] / H;        // 128
    int N = in_sizes[0] / F;        // 50000
    int E = in_sizes[2];            // 800000
    int R = in_sizes[5] / (H * H);  // 8
    int NS = R + 1;                 // 9 output slices (R relations + root)
    int ldhw = NS * H;              // 1152

    const int* srcv = ei;
    const int* dstv = ei + E;

    char* p = (char*)d_ws;
    auto alloc = [&](size_t bytes) -> char* {
        char* r = p;
        p += (bytes + 255) & ~(size_t)255;
        return r;
    };
    bf16*  HW      = (bf16*)alloc((size_t)N * ldhw * 2);
    bf16*  h       = (bf16*)alloc((size_t)N * H * 2);
    float* conv    = (float*)alloc((size_t)N * H * 4);
    bf16*  WhwT    = (bf16*)alloc((size_t)ldhw * H * 2);
    bf16*  W1T     = (bf16*)alloc((size_t)F * H * 2);
    float* qc      = (float*)alloc(129 * 4);
    int*   cnt     = (int*)alloc((size_t)N * 4);
    int*   row_off = (int*)alloc((size_t)(N + 1) * 4);
    int*   cursor  = (int*)alloc((size_t)N * 4);
    int*   csr     = (int*)alloc((size_t)E * 4);
    float* stats   = (float*)alloc(256 * 4);
    float* bnp     = (float*)alloc(256 * 4);
    int*   bsum    = (int*)alloc(256 * 4);
    if ((size_t)(p - (char*)d_ws) > ws_size) return;

    int nb = (N + 255) / 256;  // <= 256 since N <= 65536 (required by csr packing)
    int pbase = (N + 7) / 8;   // dst-partition width for XCD-local csr fill

    hipMemsetAsync(cnt, 0, (size_t)N * 4, stream);
    hipMemsetAsync(stats, 0, 256 * 4, stream);
    k_prep<<<256, 256, 0, stream>>>(W1, weight, root, W2, b2, Wo, bo, W1T, WhwT, qc, R);
    k_hist<<<1024, 256, 0, stream>>>(dstv, cnt, E);
    k_scan_blk<<<nb, 256, 0, stream>>>(cnt, bsum, N);
    k_scan_top<<<1, 256, 0, stream>>>(bsum, nb);
    k_scan_apply<<<nb, 256, 0, stream>>>(cnt, bsum, row_off, cursor, N);
    k_fill<<<1024, 256, 0, stream>>>(srcv, dstv, etype, cursor, csr, E, pbase);

    int mb = (N + 127) / 128;
    int mb64 = (N + 63) / 64;
    k_gemm0<<<mb, 256, 0, stream>>>(x, W1T, b1, h, N);

    for (int l = 0; l < 2; l++) {
        k_hwgemm<<<mb64, 256, 0, stream>>>(h, WhwT, HW, N, NS);
        k_agg3<<<(N + 1) / 2, 128, 0, stream>>>(HW, row_off, csr, bias_c, conv, N, ldhw, R);
        k_stats<<<512, 256, 0, stream>>>(conv, stats, N);
        k_bnfin<<<1, 128, 0, stream>>>(stats, gamma, beta, bnp, 1.f / (float)N);
        if (l == 0)
            k_bnrelu<<<2048, 256, 0, stream>>>(conv, bnp, h, N);
        else
            k_bnout<<<(N + 3) / 4, 256, 0, stream>>>(conv, bnp, qc, out, N);
    }
}

// Round 9
// 306.425 us; speedup vs baseline: 1.8571x; 1.7651x over previous
//
#include <hip/hip_runtime.h>
#include <stdint.h>

typedef __bf16 bf16;
typedef __bf16 bf16x8 __attribute__((ext_vector_type(8)));
typedef float f32x4 __attribute__((ext_vector_type(4)));

__device__ __forceinline__ float bfbits2f(uint32_t lo16) {
    uint32_t b = lo16 << 16;
    float f;
    __builtin_memcpy(&f, &b, 4);
    return f;
}

__device__ __forceinline__ uint32_t pack2bf(float a, float b) {
    uint32_t lo = __builtin_bit_cast(unsigned short, (bf16)a);
    uint32_t hi = __builtin_bit_cast(unsigned short, (bf16)b);
    return lo | (hi << 16);
}

__device__ __forceinline__ void gload_lds16(const void* g, void* l) {
    __builtin_amdgcn_global_load_lds((const __attribute__((address_space(1))) void*)g,
                                     (__attribute__((address_space(3))) void*)l, 16, 0, 0);
}

// ---- prep: W1T[h][f]=W1[f][h];  WcatT2[o][r*128+c]=weight[r][c][o],
// WcatT2[o][R*128+c]=root[c][o];  tail computes qc:
// qc[i]=sum_j W2[i][j]*Wo[j], qc[128]=b2.Wo+bo
__global__ void k_prep(const float* __restrict__ W1, const float* __restrict__ weight,
                       const float* __restrict__ root, const float* __restrict__ W2,
                       const float* __restrict__ b2, const float* __restrict__ Wo,
                       const float* __restrict__ bo, bf16* __restrict__ W1T,
                       bf16* __restrict__ WcatT2, float* __restrict__ qc, int R, int ldt) {
    int total = 16384 * (R + 2);
    for (int i = blockIdx.x * blockDim.x + threadIdx.x; i < total + 129; i += gridDim.x * blockDim.x) {
        if (i < 16384) {
            int f = i >> 7, h = i & 127;
            W1T[h * 128 + f] = (bf16)W1[f * 128 + h];
        } else if (i < total) {
            int j = i - 16384;
            int r = j >> 14, rem = j & 16383, c = rem >> 7, o = rem & 127;
            float v = (r < R) ? weight[(size_t)(r * 128 + c) * 128 + o] : root[c * 128 + o];
            WcatT2[(size_t)o * ldt + r * 128 + c] = (bf16)v;
        } else {
            int t = i - total;
            if (t < 128) {
                float s = 0.f;
                for (int j = 0; j < 128; j++) s += W2[t * 128 + j] * Wo[j];
                qc[t] = s;
            } else {
                float c = bo[0];
                for (int j = 0; j < 128; j++) c += b2[j] * Wo[j];
                qc[128] = c;
            }
        }
    }
}

// ---- CSR build (dst-keyed, N segments; payload (etype<<16)|src) ----
__global__ void k_hist(const int* __restrict__ dst, int* __restrict__ cnt, int E) {
    for (int e = blockIdx.x * blockDim.x + threadIdx.x; e < E; e += gridDim.x * blockDim.x)
        atomicAdd(&cnt[dst[e]], 1);
}

__global__ __launch_bounds__(256) void k_scan_blk(const int* __restrict__ cnt, int* __restrict__ bsum, int N) {
    int i = blockIdx.x * 256 + threadIdx.x;
    int v = (i < N) ? cnt[i] : 0;
#pragma unroll
    for (int d = 1; d < 64; d <<= 1) v += __shfl_xor(v, d);
    __shared__ int ws[4];
    if ((threadIdx.x & 63) == 0) ws[threadIdx.x >> 6] = v;
    __syncthreads();
    if (threadIdx.x == 0) bsum[blockIdx.x] = ws[0] + ws[1] + ws[2] + ws[3];
}

__global__ __launch_bounds__(256) void k_scan_top(int* __restrict__ bsum, int nb) {
    __shared__ int s[256];
    int t = threadIdx.x;
    int v = (t < nb) ? bsum[t] : 0;
    s[t] = v;
    __syncthreads();
#pragma unroll
    for (int d = 1; d < 256; d <<= 1) {
        int u = (t >= d) ? s[t - d] : 0;
        __syncthreads();
        s[t] += u;
        __syncthreads();
    }
    if (t < nb) bsum[t] = s[t] - v;  // exclusive
}

__global__ __launch_bounds__(256) void k_scan_apply(const int* __restrict__ cnt, const int* __restrict__ bsum,
                                                    int* __restrict__ row_off, int* __restrict__ cursor, int N) {
    int b = blockIdx.x, t = threadIdx.x;
    int i = b * 256 + t;
    int v = (i < N) ? cnt[i] : 0;
    int lane = t & 63, wid = t >> 6;
    int incl = v;
#pragma unroll
    for (int d = 1; d < 64; d <<= 1) {
        int u = __shfl_up(incl, d);
        if (lane >= d) incl += u;
    }
    __shared__ int ws[4];
    if (lane == 63) ws[wid] = incl;
    __syncthreads();
    int woff = 0;
    for (int wj = 0; wj < 4; wj++)
        if (wj < wid) woff += ws[wj];
    int excl = bsum[b] + woff + incl - v;
    if (i < N) {
        row_off[i] = excl;
        cursor[i] = excl;
        if (i == N - 1) row_off[N] = excl + v;
    }
}

// XCD-partitioned CSR fill (one XCD owns each contiguous csr region so lines
// fill fully before writeback). payload = (etype<<16)|src, requires N <= 65536.
__global__ void k_fill(const int* __restrict__ src, const int* __restrict__ dst,
                       const int* __restrict__ etype, int* __restrict__ cursor,
                       int* __restrict__ csr, int E, int pbase) {
    int p = blockIdx.x & 7;
    int bg = blockIdx.x >> 3;
    int nchunk = gridDim.x >> 3;
    int chunk = (E + nchunk - 1) / nchunk;
    int beg = bg * chunk, end = min(beg + chunk, E);
    int lo = p * pbase, hi = lo + pbase;
    for (int e = beg + (int)threadIdx.x; e < end; e += blockDim.x) {
        int d = dst[e];
        if (d >= lo && d < hi) {
            int pos = atomicAdd(&cursor[d], 1);
            csr[pos] = (etype[e] << 16) | src[e];
        }
    }
}

// ---- GEMM (layer 0): C[M x 128] = A_f32[M x 128] * B[128 x 128] (+bias), bf16 out
__global__ __launch_bounds__(256) void k_gemm0(const float* __restrict__ A, const bf16* __restrict__ BT,
                                               const float* __restrict__ bias, bf16* __restrict__ C, int M) {
    __shared__ bf16 sA[128 * 128];
    __shared__ bf16 sB[128 * 128];
    int tid = threadIdx.x;
    int m0 = blockIdx.x * 128;
#pragma unroll
    for (int i = 0; i < 8; i++) {
        int chunk = i * 256 + tid;
        int row = chunk >> 4, c16 = chunk & 15;
        int sw = ((c16 ^ (row & 7)) << 3);
        int gr = m0 + row;
        int4 va = {0, 0, 0, 0};
        if (gr < M) {
            const float* ap = A + (size_t)gr * 128 + (c16 << 3);
            float4 f0 = *reinterpret_cast<const float4*>(ap);
            float4 f1 = *reinterpret_cast<const float4*>(ap + 4);
            bf16 tmp[8] = {(bf16)f0.x, (bf16)f0.y, (bf16)f0.z, (bf16)f0.w,
                           (bf16)f1.x, (bf16)f1.y, (bf16)f1.z, (bf16)f1.w};
            __builtin_memcpy(&va, tmp, 16);
        }
        *reinterpret_cast<int4*>(&sA[row * 128 + sw]) = va;
        int4 vb = *reinterpret_cast<const int4*>(&BT[(size_t)row * 128 + (c16 << 3)]);
        *reinterpret_cast<int4*>(&sB[row * 128 + sw]) = vb;
    }
    __syncthreads();

    int lane = tid & 63, w = tid >> 6;
    int wm = (w >> 1) * 64, wn = (w & 1) * 64;
    int lr = lane & 15, lk = lane >> 4;
    f32x4 zero = {0.f, 0.f, 0.f, 0.f};
    f32x4 acc[4][4];
#pragma unroll
    for (int mi = 0; mi < 4; mi++)
#pragma unroll
        for (int ni = 0; ni < 4; ni++) acc[mi][ni] = zero;

#pragma unroll
    for (int kk = 0; kk < 4; kk++) {
        int c = (kk << 2) + lk;
        bf16x8 af[4], bfr[4];
#pragma unroll
        for (int mi = 0; mi < 4; mi++) {
            int r = wm + mi * 16 + lr;
            af[mi] = *reinterpret_cast<const bf16x8*>(&sA[r * 128 + ((c ^ (r & 7)) << 3)]);
        }
#pragma unroll
        for (int ni = 0; ni < 4; ni++) {
            int r = wn + ni * 16 + lr;
            bfr[ni] = *reinterpret_cast<const bf16x8*>(&sB[r * 128 + ((c ^ (r & 7)) << 3)]);
        }
#pragma unroll
        for (int mi = 0; mi < 4; mi++)
#pragma unroll
            for (int ni = 0; ni < 4; ni++)
                acc[mi][ni] = __builtin_amdgcn_mfma_f32_16x16x32_bf16(af[mi], bfr[ni], acc[mi][ni], 0, 0, 0);
    }

#pragma unroll
    for (int ni = 0; ni < 4; ni++) {
        int col = wn + ni * 16 + lr;
        float bia = bias[col];
#pragma unroll
        for (int mi = 0; mi < 4; mi++) {
#pragma unroll
            for (int j = 0; j < 4; j++) {
                int row = m0 + wm + mi * 16 + lk * 4 + j;
                if (row < M) C[(size_t)row * 128 + col] = (bf16)(acc[mi][ni][j] + bia);
            }
        }
    }
}

// ---- aggregation: G[n] = [agg_0[n], ..., agg_7[n]] (bf16, row length 1024)
// Branchless LDS accumulate + 4-deep pipeline; G stores NON-TEMPORAL (r5: keeps
// h L3-resident; r0 showed the 100MB G write stream evicting h -> 85MB refetch).
__global__ __launch_bounds__(128) void k_agg2(const bf16* __restrict__ h, const int* __restrict__ row_off,
                                              const int* __restrict__ csr, bf16* __restrict__ G, int N) {
    __shared__ float acc[2][8 * 128];
    int wi = threadIdx.x >> 6;
    int n = blockIdx.x * 2 + wi;
    if (n >= N) return;
    int lane = threadIdx.x & 63;
    int c0 = lane * 2;
    float* a = acc[wi];
#pragma unroll
    for (int i = 0; i < 16; i++) a[i * 64 + lane] = 0.f;
    int beg = row_off[n], end = row_off[n + 1];
    int i = beg;
    for (; i + 4 <= end; i += 4) {
        int p0 = csr[i], p1 = csr[i + 1], p2 = csr[i + 2], p3 = csr[i + 3];
        uint32_t v0 = *reinterpret_cast<const uint32_t*>(&h[(size_t)(p0 & 0xffff) * 128 + c0]);
        uint32_t v1 = *reinterpret_cast<const uint32_t*>(&h[(size_t)(p1 & 0xffff) * 128 + c0]);
        uint32_t v2 = *reinterpret_cast<const uint32_t*>(&h[(size_t)(p2 & 0xffff) * 128 + c0]);
        uint32_t v3 = *reinterpret_cast<const uint32_t*>(&h[(size_t)(p3 & 0xffff) * 128 + c0]);
        float* a0 = &a[(p0 >> 16) * 128 + c0];
        a0[0] += bfbits2f(v0 & 0xffffu); a0[1] += bfbits2f(v0 >> 16);
        float* a1 = &a[(p1 >> 16) * 128 + c0];
        a1[0] += bfbits2f(v1 & 0xffffu); a1[1] += bfbits2f(v1 >> 16);
        float* a2 = &a[(p2 >> 16) * 128 + c0];
        a2[0] += bfbits2f(v2 & 0xffffu); a2[1] += bfbits2f(v2 >> 16);
        float* a3 = &a[(p3 >> 16) * 128 + c0];
        a3[0] += bfbits2f(v3 & 0xffffu); a3[1] += bfbits2f(v3 >> 16);
    }
    for (; i < end; i++) {
        int p = csr[i];
        uint32_t v = *reinterpret_cast<const uint32_t*>(&h[(size_t)(p & 0xffff) * 128 + c0]);
        float* ap = &a[(p >> 16) * 128 + c0];
        ap[0] += bfbits2f(v & 0xffffu);
        ap[1] += bfbits2f(v >> 16);
    }
    size_t gbase = (size_t)n * 1024 + c0;
#pragma unroll
    for (int r = 0; r < 8; r++) {
        __builtin_nontemporal_store(pack2bf(a[r * 128 + c0], a[r * 128 + c0 + 1]),
                                    reinterpret_cast<uint32_t*>(&G[gbase + r * 128]));
    }
}

// ---- GEMM2 v2: conv[M x 128] = [G | h][M x K] * Wcat[K x 128] + bias_c, f32 out
// + fused BN-stats. r8 post-mortem of r5: per-K-tile s_waitcnt vmcnt(0) +
// __syncthreads (which emits its own full drain) serialized 9 HBM-latency
// G-tile fetches -> 49us @ MfmaUtil 11%, Occ 13%. v2 = T3/T4 counted-vmcnt
// double-buffer (guide m218: +38-73%): BK=64, 2 LDS buffers, prologue stages
// tiles 0,1; loop waits vmcnt(8) (current tile landed, next tile's 8 loads
// REMAIN IN FLIGHT across raw s_barrier), computes, barriers, stages t+2.
// vmcnt(0) only on the last tile. LDS 64KB -> 2 blocks/CU unchanged.
__global__ __launch_bounds__(256) void k_gemm2(const bf16* __restrict__ G, const bf16* __restrict__ hsrc,
                                               const bf16* __restrict__ BT, const float* __restrict__ bias,
                                               float* __restrict__ C, float* __restrict__ stats,
                                               int M, int K) {
    __shared__ bf16 sA[2][128 * 64];
    __shared__ bf16 sB[2][128 * 64];
    __shared__ float csum[128], csum2[128];
    int tid = threadIdx.x;
    if (tid < 128) { csum[tid] = 0.f; csum2[tid] = 0.f; }
    int m0 = blockIdx.x * 128;
    int lane = tid & 63, w = tid >> 6;
    int wm = (w >> 1) * 64, wn = (w & 1) * 64;
    int lr = lane & 15, lk = lane >> 4;
    int KT = K >> 6;          // 18 tiles of BK=64
    int KG = (K - 128) >> 6;  // 16 G tiles; tiles KG.. are the h part
    size_t ldg = (size_t)(K - 128);  // 1024 (G row stride)

    // per-thread staging coords: instr i covers chunkid = i*256+tid
    // row = chunkid>>3 (8 x 16B chunks per 64-col row), c8 = chunkid&7
    int rowi[4], csi[4], grA[4];
#pragma unroll
    for (int i = 0; i < 4; i++) {
        int chunkid = i * 256 + tid;
        rowi[i] = chunkid >> 3;
        csi[i] = ((chunkid & 7) ^ (rowi[i] & 7)) << 3;  // pre-swizzled source col
        int g = m0 + rowi[i];
        grA[i] = g < M ? g : M - 1;  // clamp; dup rows masked at C-write
    }

    auto stage = [&](int kt, int b) {
        bool lastt = (kt >= KG);
        const bf16* Abase = lastt ? hsrc : G;
        size_t ldA = lastt ? 128 : ldg;
        int ka = lastt ? ((kt - KG) << 6) : (kt << 6);
        int k0 = kt << 6;
        bf16* dA = &sA[b][(w << 6) * 8];
        bf16* dB = &sB[b][(w << 6) * 8];
#pragma unroll
        for (int i = 0; i < 4; i++) {
            gload_lds16(Abase + (size_t)grA[i] * ldA + ka + csi[i], dA + i * 2048);
            gload_lds16(&BT[(size_t)rowi[i] * K + k0 + csi[i]], dB + i * 2048);
        }
    };

    f32x4 zero = {0.f, 0.f, 0.f, 0.f};
    f32x4 acc[4][4];
#pragma unroll
    for (int mi = 0; mi < 4; mi++)
#pragma unroll
        for (int ni = 0; ni < 4; ni++) acc[mi][ni] = zero;

    stage(0, 0);
    stage(1, 1);
    for (int kt = 0; kt < KT; kt++) {
        if (kt + 1 < KT)
            asm volatile("s_waitcnt vmcnt(8)" ::: "memory");  // tile kt landed; kt+1 in flight
        else
            asm volatile("s_waitcnt vmcnt(0)" ::: "memory");  // last tile: drain
        __builtin_amdgcn_s_barrier();
        int b = kt & 1;
        const bf16* A = sA[b];
        const bf16* B = sB[b];
#pragma unroll
        for (int kk = 0; kk < 2; kk++) {
            int c = (kk << 2) + lk;
            bf16x8 af[4], bfr[4];
#pragma unroll
            for (int mi = 0; mi < 4; mi++) {
                int r = wm + mi * 16 + lr;
                af[mi] = *reinterpret_cast<const bf16x8*>(&A[r * 64 + ((c ^ (r & 7)) << 3)]);
            }
#pragma unroll
            for (int ni = 0; ni < 4; ni++) {
                int r = wn + ni * 16 + lr;
                bfr[ni] = *reinterpret_cast<const bf16x8*>(&B[r * 64 + ((c ^ (r & 7)) << 3)]);
            }
#pragma unroll
            for (int mi = 0; mi < 4; mi++)
#pragma unroll
                for (int ni = 0; ni < 4; ni++)
                    acc[mi][ni] = __builtin_amdgcn_mfma_f32_16x16x32_bf16(af[mi], bfr[ni], acc[mi][ni], 0, 0, 0);
        }
        __builtin_amdgcn_s_barrier();  // all waves done reading buf b
        if (kt + 2 < KT) stage(kt + 2, b);
    }

    float ls[4], ls2[4];
#pragma unroll
    for (int ni = 0; ni < 4; ni++) { ls[ni] = 0.f; ls2[ni] = 0.f; }
#pragma unroll
    for (int ni = 0; ni < 4; ni++) {
        int col = wn + ni * 16 + lr;
        float bia = bias[col];
#pragma unroll
        for (int mi = 0; mi < 4; mi++) {
#pragma unroll
            for (int j = 0; j < 4; j++) {
                int row = m0 + wm + mi * 16 + lk * 4 + j;
                if (row < M) {
                    float val = acc[mi][ni][j] + bia;
                    C[(size_t)row * 128 + col] = val;
                    ls[ni] += val;
                    ls2[ni] += val * val;
                }
            }
        }
    }
#pragma unroll
    for (int ni = 0; ni < 4; ni++) {
        float s = ls[ni], s2 = ls2[ni];
        s += __shfl_xor(s, 16); s += __shfl_xor(s, 32);
        s2 += __shfl_xor(s2, 16); s2 += __shfl_xor(s2, 32);
        if (lk == 0) {
            int col = wn + ni * 16 + lr;
            atomicAdd(&csum[col], s);
            atomicAdd(&csum2[col], s2);
        }
    }
    __syncthreads();
    if (tid < 128) {
        atomicAdd(&stats[tid], csum[tid]);
        atomicAdd(&stats[128 + tid], csum2[tid]);
    }
}

// ---- finalize BN coefficients: bnp[c]=scale, bnp[128+c]=shift; re-zero stats
__global__ void k_bnfin(float* __restrict__ stats, const float* __restrict__ gamma,
                        const float* __restrict__ beta, float* __restrict__ bnp, float invN) {
    int t = threadIdx.x;
    float mu = stats[t] * invN;
    float var = stats[128 + t] * invN - mu * mu;
    float sc = gamma[t] * rsqrtf(var + 1e-5f);
    bnp[t] = sc;
    bnp[128 + t] = beta[t] - mu * sc;
    stats[t] = 0.f;
    stats[128 + t] = 0.f;
}

// ---- BN + ReLU + cast to bf16 (layer 1) ----
__global__ void k_bnrelu(const float* __restrict__ conv, const float* __restrict__ bnp,
                         bf16* __restrict__ h, int N) {
    int total = N * 32;
    for (int i = blockIdx.x * blockDim.x + threadIdx.x; i < total; i += gridDim.x * blockDim.x) {
        int c4 = (i & 31) << 2;
        float4 v = *reinterpret_cast<const float4*>(&conv[(size_t)i * 4]);
        const float* vv = &v.x;
        uint64_t pk = 0;
#pragma unroll
        for (int j = 0; j < 4; j++) {
            int c = c4 + j;
            float val = fmaxf(vv[j] * bnp[c] + bnp[128 + c], 0.f);
            unsigned short us = __builtin_bit_cast(unsigned short, (bf16)val);
            pk |= (uint64_t)us << (16 * j);
        }
        *reinterpret_cast<uint64_t*>(&h[(size_t)i * 4]) = pk;
    }
}

// ---- layer 2: out[n] = sigmoid(relu(bn(conv[n])) . q + c), fused, f32 out ----
__global__ __launch_bounds__(256) void k_bnout(const float* __restrict__ conv, const float* __restrict__ bnp,
                                               const float* __restrict__ qc, float* __restrict__ out, int N) {
    int wi = threadIdx.x >> 6;
    int n = blockIdx.x * 4 + wi;
    if (n >= N) return;
    int lane = threadIdx.x & 63;
    int c0 = lane * 2;
    float2 v = *reinterpret_cast<const float2*>(&conv[(size_t)n * 128 + c0]);
    float v0 = fmaxf(v.x * bnp[c0] + bnp[128 + c0], 0.f);
    float v1 = fmaxf(v.y * bnp[c0 + 1] + bnp[128 + c0 + 1], 0.f);
    float s = v0 * qc[c0] + v1 * qc[c0 + 1];
#pragma unroll
    for (int d = 1; d < 64; d <<= 1) s += __shfl_xor(s, d);
    if (lane == 0) out[n] = 1.f / (1.f + expf(-(s + qc[128])));
}

extern "C" void kernel_launch(void* const* d_in, const int* in_sizes, int n_in,
                              void* d_out, int out_size, void* d_ws, size_t ws_size,
                              hipStream_t stream) {
    const float* x      = (const float*)d_in[0];
    const int*   ei     = (const int*)d_in[1];
    const int*   etype  = (const int*)d_in[2];
    const float* W1     = (const float*)d_in[3];
    const float* b1     = (const float*)d_in[4];
    const float* weight = (const float*)d_in[5];
    const float* root   = (const float*)d_in[6];
    const float* bias_c = (const float*)d_in[7];
    const float* gamma  = (const float*)d_in[8];
    const float* beta   = (const float*)d_in[9];
    const float* W2     = (const float*)d_in[10];
    const float* b2     = (const float*)d_in[11];
    const float* Wo     = (const float*)d_in[12];
    const float* bo     = (const float*)d_in[13];
    float* out = (float*)d_out;

    int H = in_sizes[4];            // 128
    int F = in_sizes[3] / H;        // 128
    int N = in_sizes[0] / F;        // 50000
    int E = in_sizes[2];            // 800000
    int R = in_sizes[5] / (H * H);  // 8
    int ldt = (R + 1) * H;          // 1152

    const int* srcv = ei;
    const int* dstv = ei + E;

    char* p = (char*)d_ws;
    auto alloc = [&](size_t bytes) -> char* {
        char* r = p;
        p += (bytes + 255) & ~(size_t)255;
        return r;
    };
    bf16*  G       = (bf16*)alloc((size_t)N * (R * H) * 2);
    bf16*  h       = (bf16*)alloc((size_t)N * H * 2);
    float* conv    = (float*)alloc((size_t)N * H * 4);
    bf16*  WcatT2  = (bf16*)alloc((size_t)ldt * H * 2);
    bf16*  W1T     = (bf16*)alloc((size_t)F * H * 2);
    float* qc      = (float*)alloc(129 * 4);
    int*   cnt     = (int*)alloc((size_t)N * 4);
    int*   row_off = (int*)alloc((size_t)(N + 1) * 4);
    int*   cursor  = (int*)alloc((size_t)N * 4);
    int*   csr     = (int*)alloc((size_t)E * 4);
    float* stats   = (float*)alloc(256 * 4);
    float* bnp     = (float*)alloc(256 * 4);
    int*   bsum    = (int*)alloc(256 * 4);
    if ((size_t)(p - (char*)d_ws) > ws_size) return;

    int nb = (N + 255) / 256;  // <= 256 since N <= 65536 (required by csr packing)
    int pbase = (N + 7) / 8;   // dst-partition width for XCD-local csr fill

    hipMemsetAsync(cnt, 0, (size_t)N * 4, stream);
    hipMemsetAsync(stats, 0, 256 * 4, stream);
    k_prep<<<256, 256, 0, stream>>>(W1, weight, root, W2, b2, Wo, bo, W1T, WcatT2, qc, R, ldt);
    k_hist<<<1024, 256, 0, stream>>>(dstv, cnt, E);
    k_scan_blk<<<nb, 256, 0, stream>>>(cnt, bsum, N);
    k_scan_top<<<1, 256, 0, stream>>>(bsum, nb);
    k_scan_apply<<<nb, 256, 0, stream>>>(cnt, bsum, row_off, cursor, N);
    k_fill<<<1024, 256, 0, stream>>>(srcv, dstv, etype, cursor, csr, E, pbase);

    int mb = (N + 127) / 128;
    k_gemm0<<<mb, 256, 0, stream>>>(x, W1T, b1, h, N);

    for (int l = 0; l < 2; l++) {
        k_agg2<<<(N + 1) / 2, 128, 0, stream>>>(h, row_off, csr, G, N);
        k_gemm2<<<mb, 256, 0, stream>>>(G, h, WcatT2, bias_c, conv, stats, N, ldt);
        k_bnfin<<<1, 128, 0, stream>>>(stats, gamma, beta, bnp, 1.f / (float)N);
        if (l == 0)
            k_bnrelu<<<2048, 256, 0, stream>>>(conv, bnp, h, N);
        else
            k_bnout<<<(N + 3) / 4, 256, 0, stream>>>(conv, bnp, qc, out, N);
    }
}